// Round 1
// baseline (731.162 us; speedup 1.0000x reference)
//
#include <hip/hip_runtime.h>

// Problem constants (from reference): B=4, T=512, QD=KD=E=256, H=8, L=4, DH=32
// SHAPES -> segment sizes {4096,1024,256,64}, offsets {0,4096,5120,5376,5440}, S=5440
#define Bn 4
#define Hn 8
#define Tn 512
#define Sn 5440
#define DHn 32
#define En 256

// ---------------------------------------------------------------------------
// Kernel A: qs[b,h,t,d] = (q @ Wq^T + bq) * scale ; gates[b,h,t,l] = softmax_l(q @ Wl^T + bl)
// one block per (b,t), 256 threads
// ---------------------------------------------------------------------------
__global__ __launch_bounds__(256) void proj_q_kernel(
    const float* __restrict__ q, const float* __restrict__ Wq, const float* __restrict__ bq,
    const float* __restrict__ Wl, const float* __restrict__ bl,
    float* __restrict__ qs, float* __restrict__ gates)
{
    int bt = blockIdx.x;            // b*T + t
    int b = bt >> 9;                // /512
    int t = bt & 511;
    int tid = threadIdx.x;

    __shared__ float qrow[256];
    __shared__ float lg[32];

    qrow[tid] = q[(size_t)bt * 256 + tid];
    __syncthreads();

    // qs: each thread computes one of the 256 embedding outputs
    {
        float acc = 0.f;
        const float4* w4 = (const float4*)(Wq + (size_t)tid * 256);
        #pragma unroll 8
        for (int i = 0; i < 64; i++) {
            float4 w = w4[i];
            acc += qrow[i*4+0]*w.x + qrow[i*4+1]*w.y + qrow[i*4+2]*w.z + qrow[i*4+3]*w.w;
        }
        const float scale = 0.17677669529663687f;   // 32^-0.5
        int h = tid >> 5, d = tid & 31;
        qs[(((size_t)b*Hn + h)*Tn + t)*DHn + d] = (acc + bq[tid]) * scale;
    }

    // gate logits: 32 outputs
    if (tid < 32) {
        float acc = 0.f;
        const float4* w4 = (const float4*)(Wl + (size_t)tid * 256);
        #pragma unroll 8
        for (int i = 0; i < 64; i++) {
            float4 w = w4[i];
            acc += qrow[i*4+0]*w.x + qrow[i*4+1]*w.y + qrow[i*4+2]*w.z + qrow[i*4+3]*w.w;
        }
        lg[tid] = acc + bl[tid];
    }
    __syncthreads();

    if (tid < 8) {  // h = tid ; softmax over 4 levels
        float x0 = lg[tid*4+0], x1 = lg[tid*4+1], x2 = lg[tid*4+2], x3 = lg[tid*4+3];
        float mx = fmaxf(fmaxf(x0,x1), fmaxf(x2,x3));
        float e0 = __expf(x0-mx), e1 = __expf(x1-mx), e2 = __expf(x2-mx), e3 = __expf(x3-mx);
        float inv = 1.f / (e0+e1+e2+e3);
        float* g = gates + (((size_t)b*Hn + tid)*Tn + t)*4;
        g[0] = e0*inv; g[1] = e1*inv; g[2] = e2*inv; g[3] = e3*inv;
    }
}

// ---------------------------------------------------------------------------
// Tiled fp32 GEMM: C[M,256] = A[M,256] @ W[256,256]^T + bias
// OMODE 0: scatter to [B,H,Srows,DH]  (b=m/Sn, s=m%Sn, h=e>>5, d=e&31)
// OMODE 1: plain row-major out[m*256+e]
// BM=128, BN=64, BK=16; 256 threads; 8x4 outputs/thread
// ---------------------------------------------------------------------------
template<int OMODE>
__global__ __launch_bounds__(256) void gemm_nt(
    const float* __restrict__ A, const float* __restrict__ W,
    const float* __restrict__ bias, float* __restrict__ out, int M)
{
    __shared__ float As[16][132];   // [k][m], padded
    __shared__ float Bs[16][68];    // [k][e], padded

    int tid = threadIdx.x;
    int row0 = blockIdx.x * 128;
    int col0 = blockIdx.y * 64;
    int ty = tid >> 4, tx = tid & 15;

    float acc[8][4] = {};

    for (int k0 = 0; k0 < 256; k0 += 16) {
        __syncthreads();
        // stage A tile: 128 rows x 16 k  (512 float4 / 256 threads = 2 each)
        #pragma unroll
        for (int i = 0; i < 2; i++) {
            int f4 = tid + i*256;
            int m = f4 >> 2, kc = (f4 & 3) * 4;
            float4 v = *(const float4*)(A + (size_t)(row0 + m)*256 + k0 + kc);
            As[kc+0][m] = v.x; As[kc+1][m] = v.y; As[kc+2][m] = v.z; As[kc+3][m] = v.w;
        }
        // stage W tile: 64 rows x 16 k (256 float4)
        {
            int e = tid >> 2, kc = (tid & 3) * 4;
            float4 v = *(const float4*)(W + (size_t)(col0 + e)*256 + k0 + kc);
            Bs[kc+0][e] = v.x; Bs[kc+1][e] = v.y; Bs[kc+2][e] = v.z; Bs[kc+3][e] = v.w;
        }
        __syncthreads();
        #pragma unroll
        for (int kk = 0; kk < 16; kk++) {
            float4 a0 = *(const float4*)&As[kk][ty*8];
            float4 a1 = *(const float4*)&As[kk][ty*8+4];
            float4 b0 = *(const float4*)&Bs[kk][tx*4];
            float a[8] = {a0.x,a0.y,a0.z,a0.w,a1.x,a1.y,a1.z,a1.w};
            float bb[4] = {b0.x,b0.y,b0.z,b0.w};
            #pragma unroll
            for (int i = 0; i < 8; i++)
                #pragma unroll
                for (int j = 0; j < 4; j++)
                    acc[i][j] = fmaf(a[i], bb[j], acc[i][j]);
        }
    }

    #pragma unroll
    for (int i = 0; i < 8; i++) {
        int m = row0 + ty*8 + i;
        #pragma unroll
        for (int j = 0; j < 4; j++) {
            int e = col0 + tx*4 + j;
            float v = acc[i][j] + bias[e];
            if (OMODE == 0) {
                int b = m / Sn; int s = m - b * Sn;
                out[(((size_t)b*Hn + (e >> 5))*Sn + s)*DHn + (e & 31)] = v;
            } else {
                out[(size_t)m*256 + e] = v;
            }
        }
    }
}

// ---------------------------------------------------------------------------
// Kernel C: fused scores -> segmented softmax * gate -> attn store + PV
// block = one (b,h) x 16 q-rows; 256 threads; thread = (row r = tid>>4, u = tid&15)
// Two passes over S in 64-wide chunks (chunks never straddle segment bounds).
// ---------------------------------------------------------------------------
__global__ __launch_bounds__(256, 4) void attn_fused(
    const float* __restrict__ qs, const float* __restrict__ ks,
    const float* __restrict__ vs, const float* __restrict__ gates,
    float* __restrict__ attn_out, float* __restrict__ o_tmp)
{
    int bid = blockIdx.x;           // (b*8+h)*32 + tt
    int bh = bid >> 5;
    int tt = bid & 31;
    int b = bh >> 3, h = bh & 7;
    int t0 = tt << 4;
    int tid = threadIdx.x;
    int r = tid >> 4, u = tid & 15;

    __shared__ float kbuf[64][36];
    __shared__ float vbuf[64][36];
    __shared__ float attn_s[16][68];
    __shared__ float msh[16][4], lsh[16][4];

    // q row -> registers (32 floats)
    float4 qreg[8];
    {
        const float4* q4 = (const float4*)(qs + (((size_t)bh)*Tn + t0 + r)*DHn);
        #pragma unroll
        for (int i = 0; i < 8; i++) qreg[i] = q4[i];
    }

    const float* kbase = ks + (size_t)bh * Sn * DHn;
    const float* vbase = vs + (size_t)bh * Sn * DHn;

    // ---- pass 1: per-segment online max / sumexp ----
    float m_run = -1e30f, l_run = 0.f;
    int cur = 0;
    for (int c = 0; c < 85; c++) {
        int seg = (c < 64) ? 0 : (c < 80) ? 1 : (c < 84) ? 2 : 3;
        if (seg != cur) {
            if (u == 0) { msh[r][cur] = m_run; lsh[r][cur] = l_run; }
            m_run = -1e30f; l_run = 0.f; cur = seg;
        }
        __syncthreads();
        {
            const float4* src = (const float4*)(kbase + (size_t)c * 64 * DHn);
            #pragma unroll
            for (int i = 0; i < 2; i++) {
                int f4 = tid + i*256;
                int row = f4 >> 3, cc = (f4 & 7) * 4;
                *(float4*)&kbuf[row][cc] = src[f4];
            }
        }
        __syncthreads();

        float s[4];
        #pragma unroll
        for (int k = 0; k < 4; k++) {
            int j = u + k*16;
            float acc = 0.f;
            #pragma unroll
            for (int i = 0; i < 8; i++) {
                float4 kv = *(const float4*)&kbuf[j][i*4];
                acc += qreg[i].x*kv.x + qreg[i].y*kv.y + qreg[i].z*kv.z + qreg[i].w*kv.w;
            }
            s[k] = acc;
        }
        float cm = fmaxf(fmaxf(s[0],s[1]), fmaxf(s[2],s[3]));
        #pragma unroll
        for (int w = 1; w < 16; w <<= 1) cm = fmaxf(cm, __shfl_xor(cm, w, 16));
        float mn = fmaxf(m_run, cm);
        float ps = __expf(s[0]-mn) + __expf(s[1]-mn) + __expf(s[2]-mn) + __expf(s[3]-mn);
        #pragma unroll
        for (int w = 1; w < 16; w <<= 1) ps += __shfl_xor(ps, w, 16);
        l_run = l_run * __expf(m_run - mn) + ps;
        m_run = mn;
    }
    if (u == 0) { msh[r][3] = m_run; lsh[r][3] = l_run; }
    __syncthreads();

    float mreg[4], coef[4];
    {
        const float* g = gates + (((size_t)bh)*Tn + t0 + r)*4;
        #pragma unroll
        for (int sg = 0; sg < 4; sg++) { mreg[sg] = msh[r][sg]; coef[sg] = g[sg] / lsh[r][sg]; }
    }

    float* arow = attn_out + (((size_t)bh)*Tn + t0 + r)*Sn;
    float acc0 = 0.f, acc1 = 0.f;

    // ---- pass 2: recompute scores, write attn, accumulate PV ----
    for (int c = 0; c < 85; c++) {
        int seg = (c < 64) ? 0 : (c < 80) ? 1 : (c < 84) ? 2 : 3;
        __syncthreads();
        {
            const float4* srck = (const float4*)(kbase + (size_t)c * 64 * DHn);
            const float4* srcv = (const float4*)(vbase + (size_t)c * 64 * DHn);
            #pragma unroll
            for (int i = 0; i < 2; i++) {
                int f4 = tid + i*256;
                int row = f4 >> 3, cc = (f4 & 7) * 4;
                *(float4*)&kbuf[row][cc] = srck[f4];
                *(float4*)&vbuf[row][cc] = srcv[f4];
            }
        }
        __syncthreads();

        #pragma unroll
        for (int k = 0; k < 4; k++) {
            int j = u + k*16;
            float acc = 0.f;
            #pragma unroll
            for (int i = 0; i < 8; i++) {
                float4 kv = *(const float4*)&kbuf[j][i*4];
                acc += qreg[i].x*kv.x + qreg[i].y*kv.y + qreg[i].z*kv.z + qreg[i].w*kv.w;
            }
            float a = __expf(acc - mreg[seg]) * coef[seg];
            attn_s[r][j] = a;
            arow[c*64 + j] = a;
        }
        __syncthreads();

        #pragma unroll
        for (int j4 = 0; j4 < 16; j4++) {
            float4 av = *(const float4*)&attn_s[r][j4*4];
            float2 v0 = *(const float2*)&vbuf[j4*4+0][u*2];
            float2 v1 = *(const float2*)&vbuf[j4*4+1][u*2];
            float2 v2 = *(const float2*)&vbuf[j4*4+2][u*2];
            float2 v3 = *(const float2*)&vbuf[j4*4+3][u*2];
            acc0 += av.x*v0.x + av.y*v1.x + av.z*v2.x + av.w*v3.x;
            acc1 += av.x*v0.y + av.y*v1.y + av.z*v2.y + av.w*v3.y;
        }
    }

    float* orow = o_tmp + ((size_t)(b*Tn + t0 + r))*En + h*DHn + u*2;
    orow[0] = acc0; orow[1] = acc1;
}

// ---------------------------------------------------------------------------
extern "C" void kernel_launch(void* const* d_in, const int* in_sizes, int n_in,
                              void* d_out, int out_size, void* d_ws, size_t ws_size,
                              hipStream_t stream)
{
    const float* q  = (const float*)d_in[0];
    const float* k  = (const float*)d_in[1];
    const float* v  = (const float*)d_in[2];
    const float* Wq = (const float*)d_in[3];
    const float* bq = (const float*)d_in[4];
    const float* Wk = (const float*)d_in[5];
    const float* bk = (const float*)d_in[6];
    const float* Wv = (const float*)d_in[7];
    const float* bv = (const float*)d_in[8];
    const float* Wo = (const float*)d_in[9];
    const float* bo = (const float*)d_in[10];
    const float* Wl = (const float*)d_in[11];
    const float* bl = (const float*)d_in[12];

    float* out  = (float*)d_out;                         // [B,T,256]
    float* attn = out + (size_t)Bn*Tn*256;               // [B,H,T,S]

    // workspace layout (floats): qs | gates | ks | vs | o_tmp  (~46.8 MB)
    float* ws    = (float*)d_ws;
    float* qs    = ws;                                   // 524288
    float* gates = qs + (size_t)Bn*Hn*Tn*DHn;            // 65536
    float* ks    = gates + (size_t)Bn*Hn*Tn*4;           // 5570560
    float* vsb   = ks + (size_t)Bn*Hn*Sn*DHn;            // 5570560
    float* o_tmp = vsb + (size_t)Bn*Hn*Sn*DHn;           // 524288

    proj_q_kernel<<<Bn*Tn, 256, 0, stream>>>(q, Wq, bq, Wl, bl, qs, gates);
    gemm_nt<0><<<dim3((Bn*Sn)/128, 4, 1), 256, 0, stream>>>(k, Wk, bk, ks,  Bn*Sn);
    gemm_nt<0><<<dim3((Bn*Sn)/128, 4, 1), 256, 0, stream>>>(v, Wv, bv, vsb, Bn*Sn);
    attn_fused<<<Bn*Hn*(Tn/16), 256, 0, stream>>>(qs, ks, vsb, gates, attn, o_tmp);
    gemm_nt<1><<<dim3((Bn*Tn)/128, 4, 1), 256, 0, stream>>>(o_tmp, Wo, bo, out, Bn*Tn);
}

// Round 2
// 267.626 us; speedup vs baseline: 2.7320x; 2.7320x over previous
//
#include <hip/hip_runtime.h>

// B=4, T=512, QD=KD=E=256, H=8, L=4, DH=32
// segment sizes {4096,1024,256,64} -> 64-key chunks: seg0 c<64, seg1 c<80, seg2 c<84, seg3 c=84
#define Bn 4
#define Hn 8
#define Tn 512
#define Sn 5440
#define DHn 32
#define En 256

typedef short bf16x8 __attribute__((ext_vector_type(8)));
typedef float f32x4 __attribute__((ext_vector_type(4)));

static __device__ __forceinline__ unsigned short f2bf(float f) {
    union { float f; unsigned u; } c; c.f = f;
    unsigned r = c.u + 0x7fffu + ((c.u >> 16) & 1u);   // RNE
    return (unsigned short)(r >> 16);
}

// ---------------------------------------------------------------------------
// Kernel A: qs(bf16, scaled) [B,H,T,DH] + gates fp32 [B,H,T,4]
// ---------------------------------------------------------------------------
__global__ __launch_bounds__(256) void proj_q_kernel(
    const float* __restrict__ q, const float* __restrict__ Wq, const float* __restrict__ bq,
    const float* __restrict__ Wl, const float* __restrict__ bl,
    unsigned short* __restrict__ qs, float* __restrict__ gates)
{
    int bt = blockIdx.x;
    int b = bt >> 9, t = bt & 511;
    int tid = threadIdx.x;

    __shared__ float qrow[256];
    __shared__ float lg[32];

    qrow[tid] = q[(size_t)bt * 256 + tid];
    __syncthreads();

    {
        float acc = 0.f;
        const float4* w4 = (const float4*)(Wq + (size_t)tid * 256);
        #pragma unroll 8
        for (int i = 0; i < 64; i++) {
            float4 w = w4[i];
            acc += qrow[i*4+0]*w.x + qrow[i*4+1]*w.y + qrow[i*4+2]*w.z + qrow[i*4+3]*w.w;
        }
        const float scale = 0.17677669529663687f;   // 32^-0.5
        int h = tid >> 5, d = tid & 31;
        qs[(((size_t)b*Hn + h)*Tn + t)*DHn + d] = f2bf((acc + bq[tid]) * scale);
    }

    if (tid < 32) {
        float acc = 0.f;
        const float4* w4 = (const float4*)(Wl + (size_t)tid * 256);
        #pragma unroll 8
        for (int i = 0; i < 64; i++) {
            float4 w = w4[i];
            acc += qrow[i*4+0]*w.x + qrow[i*4+1]*w.y + qrow[i*4+2]*w.z + qrow[i*4+3]*w.w;
        }
        lg[tid] = acc + bl[tid];
    }
    __syncthreads();

    if (tid < 8) {
        float x0 = lg[tid*4+0], x1 = lg[tid*4+1], x2 = lg[tid*4+2], x3 = lg[tid*4+3];
        float mx = fmaxf(fmaxf(x0,x1), fmaxf(x2,x3));
        float e0 = __expf(x0-mx), e1 = __expf(x1-mx), e2 = __expf(x2-mx), e3 = __expf(x3-mx);
        float inv = 1.f / (e0+e1+e2+e3);
        float* g = gates + (((size_t)b*Hn + tid)*Tn + t)*4;
        g[0] = e0*inv; g[1] = e1*inv; g[2] = e2*inv; g[3] = e3*inv;
    }
}

// ---------------------------------------------------------------------------
// MFMA projection GEMM: C[M,256] = A[M,256] @ W[256,256]^T + bias
// BM=128, BN=128, BK=32, 4 waves (each 64x64). fp32 in, bf16 LDS staging.
// OMODE 0: bf16 out scatter [B,H,S,DH]     (k projection)
// OMODE 1: bf16 out scatter [B,H,DH,S]     (v projection, transposed)
// OMODE 2: fp32 out row-major [M,256]      (final Wo projection)
// ---------------------------------------------------------------------------
template<int OMODE>
__global__ __launch_bounds__(256) void proj_mfma(
    const float* __restrict__ A, const float* __restrict__ W,
    const float* __restrict__ bias, void* __restrict__ outv)
{
    __shared__ unsigned short As[128][40];   // 40-elem stride: 80B rows, conflict-free b128 frags
    __shared__ unsigned short Ws[128][40];

    int tid = threadIdx.x;
    int l = tid & 63, wid = tid >> 6;
    int wr = wid >> 1, wc = wid & 1;
    int lr = l & 15, lg = l >> 4;
    int row0 = blockIdx.x * 128, col0 = blockIdx.y * 128;

    f32x4 acc[4][4] = {};

    for (int k0 = 0; k0 < 256; k0 += 32) {
        __syncthreads();
        #pragma unroll
        for (int i = 0; i < 4; i++) {
            int f4 = tid + i*256;               // 0..1023
            int r = f4 >> 3, kc = (f4 & 7) * 4;
            float4 v = *(const float4*)(A + (size_t)(row0 + r)*256 + k0 + kc);
            ushort4 bv; bv.x=f2bf(v.x); bv.y=f2bf(v.y); bv.z=f2bf(v.z); bv.w=f2bf(v.w);
            *(ushort4*)&As[r][kc] = bv;
        }
        #pragma unroll
        for (int i = 0; i < 4; i++) {
            int f4 = tid + i*256;
            int r = f4 >> 3, kc = (f4 & 7) * 4;
            float4 v = *(const float4*)(W + (size_t)(col0 + r)*256 + k0 + kc);
            ushort4 bv; bv.x=f2bf(v.x); bv.y=f2bf(v.y); bv.z=f2bf(v.z); bv.w=f2bf(v.w);
            *(ushort4*)&Ws[r][kc] = bv;
        }
        __syncthreads();

        bf16x8 af[4], wf[4];
        #pragma unroll
        for (int i = 0; i < 4; i++) {
            af[i] = *(const bf16x8*)&As[wr*64 + i*16 + lr][lg*8];
            wf[i] = *(const bf16x8*)&Ws[wc*64 + i*16 + lr][lg*8];
        }
        #pragma unroll
        for (int i = 0; i < 4; i++)
            #pragma unroll
            for (int j = 0; j < 4; j++)
                acc[i][j] = __builtin_amdgcn_mfma_f32_16x16x32_bf16(af[i], wf[j], acc[i][j], 0, 0, 0);
    }

    #pragma unroll
    for (int i = 0; i < 4; i++) {
        int m0 = row0 + wr*64 + i*16 + lg*4;       // 4 consecutive rows (regs)
        #pragma unroll
        for (int j = 0; j < 4; j++) {
            int col = col0 + wc*64 + j*16 + lr;
            float bv = bias[col];
            if (OMODE == 0) {
                unsigned short* out = (unsigned short*)outv;
                #pragma unroll
                for (int r = 0; r < 4; r++) {
                    int m = m0 + r;
                    int b = m / Sn, s = m - b*Sn;
                    out[(((size_t)b*Hn + (col >> 5))*Sn + s)*DHn + (col & 31)] = f2bf(acc[i][j][r] + bv);
                }
            } else if (OMODE == 1) {
                unsigned short* out = (unsigned short*)outv;
                int b = m0 / Sn, s0 = m0 - b*Sn;    // 4-row pack never straddles b (5440%4==0)
                ushort4 pk;
                pk.x = f2bf(acc[i][j][0] + bv); pk.y = f2bf(acc[i][j][1] + bv);
                pk.z = f2bf(acc[i][j][2] + bv); pk.w = f2bf(acc[i][j][3] + bv);
                *(ushort4*)&out[(((size_t)b*Hn + (col >> 5))*DHn + (col & 31))*Sn + s0] = pk;
            } else {
                float* out = (float*)outv;
                #pragma unroll
                for (int r = 0; r < 4; r++)
                    out[(size_t)(m0 + r)*256 + col] = acc[i][j][r] + bv;
            }
        }
    }
}

// ---------------------------------------------------------------------------
// Fused attention: block = (b,h) x 16 q-rows, 4 waves split S by chunk%4.
// No max subtraction (scores bounded ~0.6). Two passes; MFMA for QK and PV.
// ---------------------------------------------------------------------------
#define XSUM(v) { v += __shfl_xor(v,1); v += __shfl_xor(v,2); v += __shfl_xor(v,4); v += __shfl_xor(v,8); }

__global__ __launch_bounds__(256) void attn_fused(
    const unsigned short* __restrict__ qs, const unsigned short* __restrict__ ks,
    const unsigned short* __restrict__ vt, const float* __restrict__ gates,
    float* __restrict__ attn_out, float* __restrict__ o_tmp)
{
    __shared__ char plds[4][2048];          // per-wave P tile [16][64] bf16, XOR-swizzled
    __shared__ float lsum[4][4][16];        // [wave][seg][row]
    __shared__ float denom[4][16];          // [seg][row]
    __shared__ float outred[4][16][32];     // [wave][row][d]

    int bid = blockIdx.x;
    int bh = bid >> 5, tt = bid & 31;
    int t0 = tt << 4;
    int b = bh >> 3, h = bh & 7;
    int tid = threadIdx.x;
    int l = tid & 63, w = tid >> 6;
    int lr = l & 15, lg = l >> 4;

    // Q A-fragment: lane holds Q[t0+lr][lg*8 .. +8]
    bf16x8 aq = *(const bf16x8*)(qs + ((size_t)bh*Tn + t0 + lr)*DHn + lg*8);

    const unsigned short* kb = ks + (size_t)bh * Sn * DHn;
    const unsigned short* vb = vt + (size_t)bh * DHn * Sn;

    // ---- pass 1: per-lane exp-sums per segment (no max needed) ----
    float lp0[4] = {0,0,0,0}, lp1[4] = {0,0,0,0}, lp2[4] = {0,0,0,0}, lp3[4] = {0,0,0,0};
    for (int c = w; c < 85; c += 4) {
        int seg = (c < 64) ? 0 : (c < 80) ? 1 : (c < 84) ? 2 : 3;
        float es[4] = {0,0,0,0};
        #pragma unroll
        for (int ct = 0; ct < 4; ct++) {
            bf16x8 bk = *(const bf16x8*)(kb + (size_t)(c*64 + ct*16 + lr)*DHn + lg*8);
            f32x4 s = __builtin_amdgcn_mfma_f32_16x16x32_bf16(aq, bk, (f32x4){0.f,0.f,0.f,0.f}, 0, 0, 0);
            #pragma unroll
            for (int r = 0; r < 4; r++) es[r] += __expf(s[r]);
        }
        if      (seg == 0) { for (int r = 0; r < 4; r++) lp0[r] += es[r]; }
        else if (seg == 1) { for (int r = 0; r < 4; r++) lp1[r] += es[r]; }
        else if (seg == 2) { for (int r = 0; r < 4; r++) lp2[r] += es[r]; }
        else               { for (int r = 0; r < 4; r++) lp3[r] += es[r]; }
    }
    #pragma unroll
    for (int r = 0; r < 4; r++) { XSUM(lp0[r]); XSUM(lp1[r]); XSUM(lp2[r]); XSUM(lp3[r]); }
    if (lr == 0) {
        #pragma unroll
        for (int r = 0; r < 4; r++) {
            lsum[w][0][4*lg + r] = lp0[r];
            lsum[w][1][4*lg + r] = lp1[r];
            lsum[w][2][4*lg + r] = lp2[r];
            lsum[w][3][4*lg + r] = lp3[r];
        }
    }
    __syncthreads();
    if (tid < 64) {
        int seg = tid >> 4, row = tid & 15;
        denom[seg][row] = lsum[0][seg][row] + lsum[1][seg][row] + lsum[2][seg][row] + lsum[3][seg][row];
    }
    __syncthreads();

    // per-lane coefficients gate/denom for its 4 rows, per segment
    float cf0[4], cf1[4], cf2[4], cf3[4];
    #pragma unroll
    for (int r = 0; r < 4; r++) {
        int row = 4*lg + r;
        const float* g = gates + ((size_t)bh*Tn + t0 + row)*4;
        cf0[r] = g[0] / denom[0][row];
        cf1[r] = g[1] / denom[1][row];
        cf2[r] = g[2] / denom[2][row];
        cf3[r] = g[3] / denom[3][row];
    }

    // ---- pass 2: recompute scores, write attn, PV via MFMA ----
    f32x4 acc0 = {0.f,0.f,0.f,0.f}, acc1 = {0.f,0.f,0.f,0.f};
    char* pbase = plds[w];
    for (int c = w; c < 85; c += 4) {
        int seg = (c < 64) ? 0 : (c < 80) ? 1 : (c < 84) ? 2 : 3;
        float cf[4];
        if      (seg == 0) { cf[0]=cf0[0]; cf[1]=cf0[1]; cf[2]=cf0[2]; cf[3]=cf0[3]; }
        else if (seg == 1) { cf[0]=cf1[0]; cf[1]=cf1[1]; cf[2]=cf1[2]; cf[3]=cf1[3]; }
        else if (seg == 2) { cf[0]=cf2[0]; cf[1]=cf2[1]; cf[2]=cf2[2]; cf[3]=cf2[3]; }
        else               { cf[0]=cf3[0]; cf[1]=cf3[1]; cf[2]=cf3[2]; cf[3]=cf3[3]; }

        #pragma unroll
        for (int ct = 0; ct < 4; ct++) {
            bf16x8 bk = *(const bf16x8*)(kb + (size_t)(c*64 + ct*16 + lr)*DHn + lg*8);
            f32x4 s = __builtin_amdgcn_mfma_f32_16x16x32_bf16(aq, bk, (f32x4){0.f,0.f,0.f,0.f}, 0, 0, 0);
            #pragma unroll
            for (int r = 0; r < 4; r++) {
                float a = __expf(s[r]) * cf[r];
                int row = 4*lg + r;
                attn_out[((size_t)bh*Tn + t0 + row)*Sn + c*64 + ct*16 + lr] = a;
                int boff = (row*128 + (ct*16 + lr)*2) ^ ((row & 7) << 4);
                *(unsigned short*)(pbase + boff) = f2bf(a);
            }
        }
        // PV: out[16q x 32d] += P[16q x 64k] * V[64k x 32d]
        #pragma unroll
        for (int hc = 0; hc < 2; hc++) {
            int boff = (lr*128 + (hc*32 + lg*8)*2) ^ ((lr & 7) << 4);
            bf16x8 pa = *(const bf16x8*)(pbase + boff);
            bf16x8 v0 = *(const bf16x8*)(vb + (size_t)lr*Sn        + c*64 + hc*32 + lg*8);
            bf16x8 v1 = *(const bf16x8*)(vb + (size_t)(16+lr)*Sn   + c*64 + hc*32 + lg*8);
            acc0 = __builtin_amdgcn_mfma_f32_16x16x32_bf16(pa, v0, acc0, 0, 0, 0);
            acc1 = __builtin_amdgcn_mfma_f32_16x16x32_bf16(pa, v1, acc1, 0, 0, 0);
        }
    }

    // cross-wave PV reduction
    #pragma unroll
    for (int r = 0; r < 4; r++) {
        outred[w][4*lg + r][lr]      = acc0[r];
        outred[w][4*lg + r][16 + lr] = acc1[r];
    }
    __syncthreads();
    #pragma unroll
    for (int i = 0; i < 2; i++) {
        int idx = tid + i*256;
        int row = idx >> 5, d = idx & 31;
        float sum = outred[0][row][d] + outred[1][row][d] + outred[2][row][d] + outred[3][row][d];
        o_tmp[((size_t)(b*Tn + t0 + row))*En + h*DHn + d] = sum;
    }
}

// ---------------------------------------------------------------------------
extern "C" void kernel_launch(void* const* d_in, const int* in_sizes, int n_in,
                              void* d_out, int out_size, void* d_ws, size_t ws_size,
                              hipStream_t stream)
{
    const float* q  = (const float*)d_in[0];
    const float* k  = (const float*)d_in[1];
    const float* v  = (const float*)d_in[2];
    const float* Wq = (const float*)d_in[3];
    const float* bq = (const float*)d_in[4];
    const float* Wk = (const float*)d_in[5];
    const float* bk = (const float*)d_in[6];
    const float* Wv = (const float*)d_in[7];
    const float* bv = (const float*)d_in[8];
    const float* Wo = (const float*)d_in[9];
    const float* bo = (const float*)d_in[10];
    const float* Wl = (const float*)d_in[11];
    const float* bl = (const float*)d_in[12];

    float* out  = (float*)d_out;                         // [B,T,256]
    float* attn = out + (size_t)Bn*Tn*256;               // [B,H,T,S]

    // workspace layout (bytes): qs | ks | vt | gates | o_tmp  (~25.7 MB)
    char* ws = (char*)d_ws;
    unsigned short* qs    = (unsigned short*)ws;                             // 1 MB
    unsigned short* ksb   = (unsigned short*)(ws + (1u<<20));                // 11,141,120 B
    unsigned short* vtb   = (unsigned short*)(ws + (1u<<20) + 11141120u);
    float*          gates = (float*)(ws + (1u<<20) + 2u*11141120u);          // 262,144 B
    float*          o_tmp = (float*)(ws + (1u<<20) + 2u*11141120u + 262144u);

    proj_q_kernel<<<Bn*Tn, 256, 0, stream>>>(q, Wq, bq, Wl, bl, qs, gates);
    proj_mfma<0><<<dim3((Bn*Sn)/128, 2), 256, 0, stream>>>(k, Wk, bk, ksb);
    proj_mfma<1><<<dim3((Bn*Sn)/128, 2), 256, 0, stream>>>(v, Wv, bv, vtb);
    attn_fused<<<Bn*Hn*(Tn/16), 256, 0, stream>>>(qs, ksb, vtb, gates, attn, o_tmp);
    proj_mfma<2><<<dim3((Bn*Tn)/128, 2), 256, 0, stream>>>(o_tmp, Wo, bo, out);
}

// Round 3
// 191.194 us; speedup vs baseline: 3.8242x; 1.3998x over previous
//
#include <hip/hip_runtime.h>

// B=4, T=512, QD=KD=E=256, H=8, L=4, DH=32
// segments {4096,1024,256,64} -> 64-key chunks: seg0 c<64, seg1 c<80, seg2 c<84, seg3 c=84
#define Bn 4
#define Hn 8
#define Tn 512
#define Sn 5440
#define DHn 32
#define En 256

typedef short bf16x8 __attribute__((ext_vector_type(8)));
typedef float f32x4 __attribute__((ext_vector_type(4)));

static __device__ __forceinline__ unsigned short f2bf(float f) {
    union { float f; unsigned u; } c; c.f = f;
    unsigned r = c.u + 0x7fffu + ((c.u >> 16) & 1u);   // RNE
    return (unsigned short)(r >> 16);
}

// ---------------------------------------------------------------------------
// gates: [B,H,T,4] = softmax_l((q @ Wl^T + bl) reshaped). 8 q-rows per block.
// ---------------------------------------------------------------------------
__global__ __launch_bounds__(256) void gates_kernel(
    const float* __restrict__ q, const float* __restrict__ Wl,
    const float* __restrict__ bl, float* __restrict__ gates)
{
    __shared__ float qr[8][256];
    __shared__ float lgs[8][32];
    int tid = threadIdx.x;
    int bt0 = blockIdx.x * 8;

    {
        const float4* src = (const float4*)(q + (size_t)bt0 * 256);
        float4* dst = (float4*)&qr[0][0];
        dst[tid] = src[tid];
        dst[tid + 256] = src[tid + 256];
    }
    __syncthreads();

    int r = tid >> 5, o = tid & 31;
    float acc = 0.f;
    const float4* w4 = (const float4*)(Wl + (size_t)o * 256);
    const float4* q4 = (const float4*)&qr[r][0];
    #pragma unroll 8
    for (int i = 0; i < 64; i++) {
        float4 w = w4[i]; float4 qq = q4[i];
        acc += qq.x*w.x + qq.y*w.y + qq.z*w.z + qq.w*w.w;
    }
    lgs[r][o] = acc + bl[o];
    __syncthreads();

    if (tid < 64) {
        int rr = tid >> 3, h = tid & 7;
        float x0 = lgs[rr][h*4+0], x1 = lgs[rr][h*4+1], x2 = lgs[rr][h*4+2], x3 = lgs[rr][h*4+3];
        float mx = fmaxf(fmaxf(x0,x1), fmaxf(x2,x3));
        float e0 = __expf(x0-mx), e1 = __expf(x1-mx), e2 = __expf(x2-mx), e3 = __expf(x3-mx);
        float inv = 1.f / (e0+e1+e2+e3);
        int bt = bt0 + rr; int b = bt >> 9, t = bt & 511;
        float* g = gates + (((size_t)b*Hn + h)*Tn + t)*4;
        g[0] = e0*inv; g[1] = e1*inv; g[2] = e2*inv; g[3] = e3*inv;
    }
}

// ---------------------------------------------------------------------------
// MFMA GEMM mainloop: C[128,128] tile of A[M,256] @ W[256,256]^T
// ---------------------------------------------------------------------------
static __device__ __forceinline__ void gemm_core(
    const float* __restrict__ A, const float* __restrict__ W,
    int row0, int col0, int tid, int wr, int wc, int lr, int lg,
    unsigned short (*As)[40], unsigned short (*Ws)[40], f32x4 acc[4][4])
{
    for (int k0 = 0; k0 < 256; k0 += 32) {
        __syncthreads();
        #pragma unroll
        for (int i = 0; i < 4; i++) {
            int f4 = tid + i*256;
            int r = f4 >> 3, kc = (f4 & 7) * 4;
            float4 v = *(const float4*)(A + (size_t)(row0 + r)*256 + k0 + kc);
            ushort4 bv; bv.x=f2bf(v.x); bv.y=f2bf(v.y); bv.z=f2bf(v.z); bv.w=f2bf(v.w);
            *(ushort4*)&As[r][kc] = bv;
        }
        #pragma unroll
        for (int i = 0; i < 4; i++) {
            int f4 = tid + i*256;
            int r = f4 >> 3, kc = (f4 & 7) * 4;
            float4 v = *(const float4*)(W + (size_t)(col0 + r)*256 + k0 + kc);
            ushort4 bv; bv.x=f2bf(v.x); bv.y=f2bf(v.y); bv.z=f2bf(v.z); bv.w=f2bf(v.w);
            *(ushort4*)&Ws[r][kc] = bv;
        }
        __syncthreads();

        bf16x8 af[4], wf[4];
        #pragma unroll
        for (int i = 0; i < 4; i++) {
            af[i] = *(const bf16x8*)&As[wr*64 + i*16 + lr][lg*8];
            wf[i] = *(const bf16x8*)&Ws[wc*64 + i*16 + lr][lg*8];
        }
        #pragma unroll
        for (int i = 0; i < 4; i++)
            #pragma unroll
            for (int j = 0; j < 4; j++)
                acc[i][j] = __builtin_amdgcn_mfma_f32_16x16x32_bf16(af[i], wf[j], acc[i][j], 0, 0, 0);
    }
}

// z=0: k -> ks [B,H,S,DH] bf16 ; z=1: v -> vt [B,H,DH,S] bf16 ; z=2: q -> qs [B,H,T,DH] bf16 (scaled)
__global__ __launch_bounds__(256) void proj_kvq(
    const float* __restrict__ kin, const float* __restrict__ Wk, const float* __restrict__ bk,
    const float* __restrict__ vin, const float* __restrict__ Wv, const float* __restrict__ bv,
    const float* __restrict__ qin, const float* __restrict__ Wq, const float* __restrict__ bq,
    unsigned short* __restrict__ ks_out, unsigned short* __restrict__ vt_out,
    unsigned short* __restrict__ qs_out)
{
    int mode = blockIdx.z;
    if (mode == 2 && blockIdx.x >= 16) return;

    __shared__ unsigned short As[128][40];
    __shared__ unsigned short Ws[128][40];

    const float* A    = (mode == 0) ? kin : (mode == 1) ? vin : qin;
    const float* W    = (mode == 0) ? Wk  : (mode == 1) ? Wv  : Wq;
    const float* bias = (mode == 0) ? bk  : (mode == 1) ? bv  : bq;

    int tid = threadIdx.x;
    int l = tid & 63, wid = tid >> 6;
    int wr = wid >> 1, wc = wid & 1;
    int lr = l & 15, lg = l >> 4;
    int row0 = blockIdx.x * 128, col0 = blockIdx.y * 128;

    f32x4 acc[4][4] = {};
    gemm_core(A, W, row0, col0, tid, wr, wc, lr, lg, As, Ws, acc);

    const float qscale = 0.17677669529663687f * 1.4426950408889634f;  // dh^-0.5 * log2(e)

    #pragma unroll
    for (int i = 0; i < 4; i++) {
        int m0 = row0 + wr*64 + i*16 + lg*4;
        #pragma unroll
        for (int j = 0; j < 4; j++) {
            int col = col0 + wc*64 + j*16 + lr;
            float bvv = bias[col];
            if (mode == 0) {
                #pragma unroll
                for (int r = 0; r < 4; r++) {
                    int m = m0 + r;
                    int b = m / Sn, s = m - b*Sn;
                    ks_out[(((size_t)b*Hn + (col >> 5))*Sn + s)*DHn + (col & 31)] = f2bf(acc[i][j][r] + bvv);
                }
            } else if (mode == 1) {
                int b = m0 / Sn, s0 = m0 - b*Sn;    // 4-row pack never straddles b
                ushort4 pk;
                pk.x = f2bf(acc[i][j][0] + bvv); pk.y = f2bf(acc[i][j][1] + bvv);
                pk.z = f2bf(acc[i][j][2] + bvv); pk.w = f2bf(acc[i][j][3] + bvv);
                *(ushort4*)&vt_out[(((size_t)b*Hn + (col >> 5))*DHn + (col & 31))*Sn + s0] = pk;
            } else {
                #pragma unroll
                for (int r = 0; r < 4; r++) {
                    int m = m0 + r;
                    int b = m >> 9, t = m & 511;
                    qs_out[(((size_t)b*Hn + (col >> 5))*Tn + t)*DHn + (col & 31)] = f2bf((acc[i][j][r] + bvv) * qscale);
                }
            }
        }
    }
}

// final projection: out[M,256] = o_tmp @ Wo^T + bo, fp32 out
__global__ __launch_bounds__(256) void proj_out(
    const float* __restrict__ A, const float* __restrict__ W,
    const float* __restrict__ bias, float* __restrict__ out)
{
    __shared__ unsigned short As[128][40];
    __shared__ unsigned short Ws[128][40];

    int tid = threadIdx.x;
    int l = tid & 63, wid = tid >> 6;
    int wr = wid >> 1, wc = wid & 1;
    int lr = l & 15, lg = l >> 4;
    int row0 = blockIdx.x * 128, col0 = blockIdx.y * 128;

    f32x4 acc[4][4] = {};
    gemm_core(A, W, row0, col0, tid, wr, wc, lr, lg, As, Ws, acc);

    #pragma unroll
    for (int i = 0; i < 4; i++) {
        int m0 = row0 + wr*64 + i*16 + lg*4;
        #pragma unroll
        for (int j = 0; j < 4; j++) {
            int col = col0 + wc*64 + j*16 + lr;
            float bvv = bias[col];
            #pragma unroll
            for (int r = 0; r < 4; r++)
                out[(size_t)(m0 + r)*256 + col] = acc[i][j][r] + bvv;
        }
    }
}

// ---------------------------------------------------------------------------
// Fused attention, swapped-QK layout. Block = (b,h) x 16 q-rows, 4 waves
// split S by chunk%4. qs is pre-scaled by dh^-0.5*log2(e) -> exp2.
// C^T layout: lane holds 4 consecutive KEYS (4*lg+r) for q-row lr.
// ---------------------------------------------------------------------------
__global__ __launch_bounds__(256) void attn_fused(
    const unsigned short* __restrict__ qs, const unsigned short* __restrict__ ks,
    const unsigned short* __restrict__ vt, const float* __restrict__ gates,
    float* __restrict__ attn_out, float* __restrict__ o_tmp)
{
    __shared__ char plds[4][2048];          // per-wave P tile [16 rows][64 keys] bf16, XOR-swizzled
    __shared__ float lsum[4][4][16];        // [wave][seg][row]
    __shared__ float denom[4][16];          // [seg][row]
    __shared__ float outred[4][16][32];     // [wave][row][d]

    int bid = blockIdx.x;
    int bh = bid >> 5, tt = bid & 31;
    int t0 = tt << 4;
    int b = bh >> 3, h = bh & 7;
    int tid = threadIdx.x;
    int l = tid & 63, w = tid >> 6;
    int lr = l & 15, lg = l >> 4;

    // Q B-fragment: lane holds Q[t0+lr][lg*8..+8]
    bf16x8 aq = *(const bf16x8*)(qs + ((size_t)bh*Tn + t0 + lr)*DHn + lg*8);
    const unsigned short* kb = ks + (size_t)bh * Sn * DHn;
    const unsigned short* vb = vt + (size_t)bh * DHn * Sn;

    // ---- pass 1: per-lane exp2 sums per segment ----
    float lp[4] = {0.f, 0.f, 0.f, 0.f};
    #pragma unroll 2
    for (int c = w; c < 85; c += 4) {
        int seg = (c < 64) ? 0 : (c < 80) ? 1 : (c < 84) ? 2 : 3;
        float es = 0.f;
        #pragma unroll
        for (int ct = 0; ct < 4; ct++) {
            bf16x8 bk = *(const bf16x8*)(kb + (size_t)(c*64 + ct*16 + lr)*DHn + lg*8);
            f32x4 s = __builtin_amdgcn_mfma_f32_16x16x32_bf16(bk, aq, (f32x4){0.f,0.f,0.f,0.f}, 0, 0, 0);
            es += exp2f(s[0]) + exp2f(s[1]) + exp2f(s[2]) + exp2f(s[3]);
        }
        lp[seg] += es;
    }
    #pragma unroll
    for (int sg = 0; sg < 4; sg++) {
        float v = lp[sg];
        v += __shfl_xor(v, 16); v += __shfl_xor(v, 32);
        lp[sg] = v;
    }
    if (l < 16) {
        #pragma unroll
        for (int sg = 0; sg < 4; sg++) lsum[w][sg][lr] = lp[sg];
    }
    __syncthreads();
    if (tid < 64) {
        int seg = tid >> 4, row = tid & 15;
        denom[seg][row] = lsum[0][seg][row] + lsum[1][seg][row] + lsum[2][seg][row] + lsum[3][seg][row];
    }
    __syncthreads();

    float coef[4];
    {
        const float* g = gates + ((size_t)bh*Tn + t0 + lr)*4;
        #pragma unroll
        for (int sg = 0; sg < 4; sg++) coef[sg] = g[sg] / denom[sg][lr];
    }

    // ---- pass 2: recompute, write attn (float4), PV via MFMA ----
    f32x4 acc0 = {0.f,0.f,0.f,0.f}, acc1 = {0.f,0.f,0.f,0.f};
    char* pbase = plds[w];
    float* arow = attn_out + ((size_t)bh*Tn + t0 + lr)*Sn;
    int swz = (lr & 7) << 4;

    for (int c = w; c < 85; c += 4) {
        int seg = (c < 64) ? 0 : (c < 80) ? 1 : (c < 84) ? 2 : 3;
        float cf = coef[seg];

        #pragma unroll
        for (int ct = 0; ct < 4; ct++) {
            bf16x8 bk = *(const bf16x8*)(kb + (size_t)(c*64 + ct*16 + lr)*DHn + lg*8);
            f32x4 s = __builtin_amdgcn_mfma_f32_16x16x32_bf16(bk, aq, (f32x4){0.f,0.f,0.f,0.f}, 0, 0, 0);
            float4 av;
            av.x = exp2f(s[0]) * cf; av.y = exp2f(s[1]) * cf;
            av.z = exp2f(s[2]) * cf; av.w = exp2f(s[3]) * cf;
            *(float4*)(arow + c*64 + ct*16 + 4*lg) = av;
            ushort4 pk; pk.x = f2bf(av.x); pk.y = f2bf(av.y); pk.z = f2bf(av.z); pk.w = f2bf(av.w);
            *(ushort4*)(pbase + ((lr*128 + ct*32 + lg*8) ^ swz)) = pk;
        }
        // PV: out[16q x 32d] += P[16q x 64k] * V[64k x 32d]
        #pragma unroll
        for (int hc = 0; hc < 2; hc++) {
            bf16x8 pa = *(const bf16x8*)(pbase + ((lr*128 + hc*64 + lg*16) ^ swz));
            bf16x8 v0 = *(const bf16x8*)(vb + (size_t)lr*Sn      + c*64 + hc*32 + lg*8);
            bf16x8 v1 = *(const bf16x8*)(vb + (size_t)(16+lr)*Sn + c*64 + hc*32 + lg*8);
            acc0 = __builtin_amdgcn_mfma_f32_16x16x32_bf16(pa, v0, acc0, 0, 0, 0);
            acc1 = __builtin_amdgcn_mfma_f32_16x16x32_bf16(pa, v1, acc1, 0, 0, 0);
        }
    }

    // cross-wave PV reduction
    #pragma unroll
    for (int r = 0; r < 4; r++) {
        outred[w][4*lg + r][lr]      = acc0[r];
        outred[w][4*lg + r][16 + lr] = acc1[r];
    }
    __syncthreads();
    #pragma unroll
    for (int i = 0; i < 2; i++) {
        int idx = tid + i*256;
        int row = idx >> 5, d = idx & 31;
        float sum = outred[0][row][d] + outred[1][row][d] + outred[2][row][d] + outred[3][row][d];
        o_tmp[((size_t)(b*Tn + t0 + row))*En + h*DHn + d] = sum;
    }
}

// ---------------------------------------------------------------------------
extern "C" void kernel_launch(void* const* d_in, const int* in_sizes, int n_in,
                              void* d_out, int out_size, void* d_ws, size_t ws_size,
                              hipStream_t stream)
{
    const float* q  = (const float*)d_in[0];
    const float* k  = (const float*)d_in[1];
    const float* v  = (const float*)d_in[2];
    const float* Wq = (const float*)d_in[3];
    const float* bq = (const float*)d_in[4];
    const float* Wk = (const float*)d_in[5];
    const float* bk = (const float*)d_in[6];
    const float* Wv = (const float*)d_in[7];
    const float* bv = (const float*)d_in[8];
    const float* Wo = (const float*)d_in[9];
    const float* bo = (const float*)d_in[10];
    const float* Wl = (const float*)d_in[11];
    const float* bl = (const float*)d_in[12];

    float* out  = (float*)d_out;                         // [B,T,256]
    float* attn = out + (size_t)Bn*Tn*256;               // [B,H,T,S]

    // workspace: qs | ks | vt | gates | o_tmp
    char* ws = (char*)d_ws;
    unsigned short* qs    = (unsigned short*)ws;                             // 1 MB
    unsigned short* ksb   = (unsigned short*)(ws + (1u<<20));                // 11,141,120 B
    unsigned short* vtb   = (unsigned short*)(ws + (1u<<20) + 11141120u);
    float*          gates = (float*)(ws + (1u<<20) + 2u*11141120u);          // 262,144 B
    float*          o_tmp = (float*)(ws + (1u<<20) + 2u*11141120u + 262144u);

    gates_kernel<<<Bn*Tn/8, 256, 0, stream>>>(q, Wl, bl, gates);
    proj_kvq<<<dim3((Bn*Sn)/128, 2, 3), 256, 0, stream>>>(
        k, Wk, bk, v, Wv, bv, q, Wq, bq, ksb, vtb, qs);
    attn_fused<<<Bn*Hn*(Tn/16), 256, 0, stream>>>(qs, ksb, vtb, gates, attn, o_tmp);
    proj_out<<<dim3((Bn*Tn)/128, 2), 256, 0, stream>>>(o_tmp, Wo, bo, out);
}